// Round 4
// baseline (24.843 us; speedup 1.0000x reference)
//
#include <hip/hip_runtime.h>
#include <math.h>

// MAM fully-connected: out[r][o] = max_k(x[r][k]*W[o][k]) + min_k(x[r][k]*W[o][k]) + b[o]
// x: (1024, 512) f32, W: (512, 512) f32, b: (512,), out: (1024, 512) f32.
//
// v4: lane = ROW (not out). Rationale: R1-R3 were LDS-pipe-bound (~20us of
// ds_read_b128 to stream W at 1KB/32 products). With lane=row, W[o][j] is
// wave-uniform -> one uniform global_load_dwordx4 (1 cacheline, L1-hot),
// reused across all 64 lanes from VGPRs; only x streams through LDS, at
// 1 ds_read_b128 per 32*O_r products -> VALU-bound by ~2.7x.
//  - block: 64 rows x 16 outs (4 waves x O_r=4 outs), full K, grid 512
//  - x: global->LDS via global_load_lds w16, SOURCE pre-swizzled (m173),
//    LDS linear; slot s of row r holds granule s^(r&15) -> b128 reads at
//    row-stride 256B are bank-optimal (8 words/bank)
//  - inner j: 1 ds_read_b128 (1 v_xor addr) + 4 uniform W loads + 32 VALU
//    (4-deep fmax/fmin chains -> v_max3/v_min3, 2 ops/product)
//  - epilogue: transpose through padded LDS tile -> coalesced stores

#define O_TOTAL 512
#define K_TOTAL 512
#define ROWT 64                  // rows per block (= lanes)
#define NWAVE 4
#define OPW 4                    // outs per wave
#define OUTT (NWAVE * OPW)       // 16 outs per block
#define KCH 64                   // K chunk staged in LDS
#define NCHUNK (K_TOTAL / KCH)   // 8
#define NJ (KCH / 4)             // 16 j-groups per chunk

__device__ __forceinline__ void stage16(const float* g, float* lds_base, int lane) {
#if __has_builtin(__builtin_amdgcn_global_load_lds)
  (void)lane;
  __builtin_amdgcn_global_load_lds(
      (__attribute__((address_space(1))) unsigned int*)g,
      (__attribute__((address_space(3))) unsigned int*)lds_base, 16, 0, 0);
#else
  *reinterpret_cast<float4*>(lds_base + lane * 4) = *reinterpret_cast<const float4*>(g);
#endif
}

__global__ __launch_bounds__(256, 2)
void mam_fc_kernel(const float* __restrict__ x, const float* __restrict__ W,
                   const float* __restrict__ bias, float* __restrict__ out) {
  __shared__ __align__(16) float Xl[2][ROWT * KCH];   // 2 x 16 KB, slot-swizzled
  __shared__ float Ot[ROWT][OUTT + 1];                // padded transpose tile

  const int t = threadIdx.x;
  const int lane = t & 63;
  const int wv = __builtin_amdgcn_readfirstlane(t >> 6);
  const int ob = blockIdx.x & 31;       // 32 out-tiles of 16
  const int rg = blockIdx.x >> 5;       // 16 row-tiles of 64
  const int o0 = ob * OUTT;
  const int row0 = rg * ROWT;

  // ---- x staging plan: wave wv pass p covers rows wv*16+p*4+(lane>>4), slot lane&15.
  // Source granule pre-swizzled: g = s ^ (r&15); LDS dest linear (HW requirement).
  const float* srcX[4];
#pragma unroll
  for (int p = 0; p < 4; ++p) {
    const int r = wv * 16 + p * 4 + (lane >> 4);
    const int g = (lane & 15) ^ (r & 15);
    srcX[p] = x + (size_t)(row0 + r) * K_TOTAL + g * 4;
  }

  // W row pointers for this wave's 4 outs (addresses wave-uniform -> 1-line loads)
  const float* Wo[OPW];
#pragma unroll
  for (int oi = 0; oi < OPW; ++oi)
    Wo[oi] = W + (size_t)(o0 + wv * OPW + oi) * K_TOTAL;

  float amax[OPW], amin[OPW];
#pragma unroll
  for (int oi = 0; oi < OPW; ++oi) { amax[oi] = -INFINITY; amin[oi] = INFINITY; }

  // in-loop x read address: row=lane, phys slot = j ^ (lane&15); XOR fields disjoint
  const unsigned baseX = (unsigned)(lane * (KCH * 4) + (lane & 15) * 16);

  // prologue: stage chunk 0 into buf 0
#pragma unroll
  for (int p = 0; p < 4; ++p)
    stage16(srcX[p], &Xl[0][wv * 1024 + p * 256], lane);
  __syncthreads();

#pragma unroll 1
  for (int c = 0; c < NCHUNK; ++c) {
    if (c + 1 < NCHUNK) {   // prefetch next chunk into other buffer
      const int kOff = (c + 1) * KCH;
#pragma unroll
      for (int p = 0; p < 4; ++p)
        stage16(srcX[p] + kOff, &Xl[(c + 1) & 1][wv * 1024 + p * 256], lane);
    }

    const char* xb = (const char*)&Xl[c & 1][0];
#pragma unroll
    for (int j = 0; j < NJ; ++j) {
      const float4 x4 = *reinterpret_cast<const float4*>(xb + (baseX ^ (unsigned)(j * 16)));
#pragma unroll
      for (int oi = 0; oi < OPW; ++oi) {
        const float4 w4 = *reinterpret_cast<const float4*>(Wo[oi] + c * KCH + j * 4);
        const float p0 = x4.x * w4.x;
        const float p1 = x4.y * w4.y;
        const float p2 = x4.z * w4.z;
        const float p3 = x4.w * w4.w;
        // 4-deep chains -> 2x v_max3 / 2x v_min3; 8 independent chains per lane
        amax[oi] = fmaxf(fmaxf(fmaxf(fmaxf(amax[oi], p0), p1), p2), p3);
        amin[oi] = fminf(fminf(fminf(fminf(amin[oi], p0), p1), p2), p3);
      }
    }
    __syncthreads();
  }

  // ---- epilogue: transpose via padded LDS so stores coalesce ----
#pragma unroll
  for (int oi = 0; oi < OPW; ++oi)
    Ot[lane][wv * OPW + oi] = amax[oi] + amin[oi];
  __syncthreads();

  const float bv = bias[o0 + (lane & 15)];
#pragma unroll
  for (int i = 0; i < 4; ++i) {
    const int r = wv * 16 + i * 4 + (lane >> 4);
    out[(size_t)(row0 + r) * O_TOTAL + o0 + (lane & 15)] = Ot[r][lane & 15] + bv;
  }
}

extern "C" void kernel_launch(void* const* d_in, const int* in_sizes, int n_in,
                              void* d_out, int out_size, void* d_ws, size_t ws_size,
                              hipStream_t stream) {
  const float* x = (const float*)d_in[0];    // (1024, 512)
  const float* W = (const float*)d_in[1];    // (512, 512)
  const float* b = (const float*)d_in[2];    // (512,)
  float* out = (float*)d_out;                // (1024, 512)

  const int nrows = in_sizes[0] / K_TOTAL;                  // 1024
  const int nblocks = (nrows / ROWT) * (O_TOTAL / OUTT);    // 16 * 32 = 512
  mam_fc_kernel<<<dim3(nblocks), dim3(256), 0, stream>>>(x, W, b, out);
}

// Round 5
// 23.770 us; speedup vs baseline: 1.0451x; 1.0451x over previous
//
#include <hip/hip_runtime.h>
#include <math.h>

// MAM fully-connected: out[r][o] = max_k(x[r][k]*W[o][k]) + min_k(x[r][k]*W[o][k]) + b[o]
// x: (1024, 512) f32, W: (512, 512) f32, b: (512,), out: (1024, 512) f32.
//
// v5 = v3 structure (best: 22.1us) + v_pk_mul_f32 inner loop.
//  - 1024 blocks (64 outs x 8 rows), 4 waves/SIMD; lane = out
//  - W: global->LDS via global_load_lds w16, SOURCE pre-swizzled (linear LDS
//    dest per HW requirement); in-loop b128 reads at phys granule j^(lane&15)
//    -> 8 words/bank (structural optimum for b128)
//  - x: LDS-staged linear, uniform-address ds_read_b128 broadcast, imm offsets
//  - inner: per j = 1 W-read (1 v_xor) + 2 x-reads + 4 v_pk_mul_f32
//    + 4 v_max3 + 4 v_min3 -> 1.5 VALU-ops/product, 5.1us issue floor

#define O_TOTAL 512
#define K_TOTAL 512
#define OBLK 64
#define NWAVE 4
#define RPW 2                    // rows per wave
#define RPB (NWAVE * RPW)        // 8 rows per block
#define KCH 64                   // K chunk staged in LDS
#define NCHUNK (K_TOTAL / KCH)   // 8

typedef float f32x2 __attribute__((ext_vector_type(2)));

__device__ __forceinline__ f32x2 pk_mul(f32x2 a, f32x2 b) {
  f32x2 d;
  asm("v_pk_mul_f32 %0, %1, %2" : "=v"(d) : "v"(a), "v"(b));
  return d;
}

__device__ __forceinline__ void stage16(const float* g, float* lds_base, int lane) {
#if __has_builtin(__builtin_amdgcn_global_load_lds)
  (void)lane;
  __builtin_amdgcn_global_load_lds(
      (__attribute__((address_space(1))) unsigned int*)g,
      (__attribute__((address_space(3))) unsigned int*)lds_base, 16, 0, 0);
#else
  *reinterpret_cast<float4*>(lds_base + lane * 4) = *reinterpret_cast<const float4*>(g);
#endif
}

__global__ __launch_bounds__(256, 4)
void mam_fc_kernel(const float* __restrict__ x, const float* __restrict__ W,
                   const float* __restrict__ bias, float* __restrict__ out) {
  __shared__ __align__(16) float Wl[2][OBLK * KCH];   // 2 x 16 KB, granule-swizzled
  __shared__ __align__(16) float Xl[2][RPB * KCH];    // 2 x 2 KB, linear

  const int t = threadIdx.x;
  const int lane = t & 63;
  const int wv = __builtin_amdgcn_readfirstlane(t >> 6);
  const int ob = blockIdx.x & 7;        // 8 out-blocks of 64
  const int rg = blockIdx.x >> 3;       // 128 row-groups of 8
  const int o0 = ob * OBLK;
  const int rowBase = rg * RPB;

  // W staging: wave wv, pass p -> row orow = wv*16 + p*4 + (lane>>4), phys
  // granule lane&15 holds logical granule (lane&15)^(orow&15) (pre-swizzled src)
  const float* srcW[4];
  int dstWoff[4];
#pragma unroll
  for (int p = 0; p < 4; ++p) {
    const int orow = wv * 16 + p * 4 + (lane >> 4);
    const int g = (lane & 15) ^ (orow & 15);
    srcW[p] = W + (size_t)(o0 + orow) * K_TOTAL + g * 4;
    dstWoff[p] = (wv * 16 + p * 4) * KCH;
  }
  // x staging (waves 0,1): row wv*4+(lane>>4), granule lane&15, linear
  const float* srcX = x + (size_t)(rowBase + wv * 4 + (lane >> 4)) * K_TOTAL + (lane & 15) * 4;
  const int dstXoff = wv * 4 * KCH;

  float amax[RPW], amin[RPW];
#pragma unroll
  for (int r = 0; r < RPW; ++r) { amax[r] = -INFINITY; amin[r] = INFINITY; }

  const unsigned baseW = (unsigned)(lane * (KCH * 4) + (lane & 15) * 16);  // bytes
  const unsigned baseX = (unsigned)((wv * RPW) * (KCH * 4));               // bytes

  // prologue: stage chunk 0 into buf 0
#pragma unroll
  for (int p = 0; p < 4; ++p) stage16(srcW[p], &Wl[0][dstWoff[p]], lane);
  if (wv < 2) stage16(srcX, &Xl[0][dstXoff], lane);
  __syncthreads();

#pragma unroll 1
  for (int c = 0; c < NCHUNK; ++c) {
    if (c + 1 < NCHUNK) {   // prefetch next chunk into the other buffer
      const int b = (c + 1) & 1;
      const int kOff = (c + 1) * KCH;
#pragma unroll
      for (int p = 0; p < 4; ++p) stage16(srcW[p] + kOff, &Wl[b][dstWoff[p]], lane);
      if (wv < 2) stage16(srcX + kOff, &Xl[b][dstXoff], lane);
    }

    const char* wb = (const char*)&Wl[c & 1][0];
    const char* xb = (const char*)&Xl[c & 1][0];
#pragma unroll
    for (int j = 0; j < KCH / 4; ++j) {
      const float4 w4 = *reinterpret_cast<const float4*>(wb + (baseW ^ (unsigned)(j * 16)));
      const f32x2 wlo = {w4.x, w4.y}, whi = {w4.z, w4.w};
#pragma unroll
      for (int r = 0; r < RPW; ++r) {
        const float4 x4 = *reinterpret_cast<const float4*>(
            xb + baseX + r * (KCH * 4) + j * 16);          // uniform -> broadcast
        const f32x2 a = pk_mul(f32x2{x4.x, x4.y}, wlo);    // 2 products / instr
        const f32x2 b = pk_mul(f32x2{x4.z, x4.w}, whi);
        // 4-deep chains -> 2x v_max3 / 2x v_min3 per (j, r)
        amax[r] = fmaxf(fmaxf(fmaxf(fmaxf(amax[r], a.x), a.y), b.x), b.y);
        amin[r] = fminf(fminf(fminf(fminf(amin[r], a.x), a.y), b.x), b.y);
      }
    }
    __syncthreads();
  }

  const float bv = bias[o0 + lane];
#pragma unroll
  for (int r = 0; r < RPW; ++r) {
    out[(size_t)(rowBase + wv * RPW + r) * O_TOTAL + o0 + lane] =
        amax[r] + amin[r] + bv;   // lanes -> consecutive floats: coalesced
  }
}

extern "C" void kernel_launch(void* const* d_in, const int* in_sizes, int n_in,
                              void* d_out, int out_size, void* d_ws, size_t ws_size,
                              hipStream_t stream) {
  const float* x = (const float*)d_in[0];    // (1024, 512)
  const float* W = (const float*)d_in[1];    // (512, 512)
  const float* b = (const float*)d_in[2];    // (512,)
  float* out = (float*)d_out;                // (1024, 512)

  const int nrows = in_sizes[0] / K_TOTAL;                 // 1024
  const int nblocks = (O_TOTAL / OBLK) * (nrows / RPB);    // 8 * 128 = 1024
  mam_fc_kernel<<<dim3(nblocks), dim3(256), 0, stream>>>(x, W, b, out);
}